// Round 7
// baseline (277.724 us; speedup 1.0000x reference)
//
#include <hip/hip_runtime.h>
#include <hip/hip_bf16.h>

typedef unsigned short u16;
typedef unsigned int u32;
typedef __attribute__((ext_vector_type(8))) short bf16x8;   // 8 bf16 (4 VGPRs)
typedef __attribute__((ext_vector_type(4))) short bf16x4;   // 4 bf16 (2 VGPRs)
typedef __attribute__((ext_vector_type(4))) float f32x4;

#define NL 2048
#define NH 16
// HD = 64; scale 1/8 and log2(e) folded into Q pre-scale

__device__ __forceinline__ float bf2f(u16 v) {
    union { float f; unsigned u; } x; x.u = ((unsigned)v) << 16; return x.f;
}
__device__ __forceinline__ u16 f2bf(float f) {
    union { __hip_bfloat16 h; u16 u; } x; x.h = __float2bfloat16(f); return x.u;
}
// round-half-up pack of two fp32 -> packed bf16 pair (finite inputs)
__device__ __forceinline__ u32 pk2(float a, float b) {
    union { float f; u32 u; } x, y; x.f = a; y.f = b;
    return ((x.u + 0x8000u) >> 16) | ((y.u + 0x8000u) & 0xffff0000u);
}
// truncating pack (1 VALU op): low16 = hi16(lo), high16 = hi16(hi). Only for P:
// L is summed from the same packed values -> bias cancels in O = sum(pV)/sum(p).
__device__ __forceinline__ u32 pkt(float lo, float hi) {
    union { float f; u32 u; } x, y; x.f = lo; y.f = hi;
    return __builtin_amdgcn_perm(y.u, x.u, 0x07060302u);
}
#if __has_builtin(__builtin_amdgcn_exp2f)
#define EXP2F(x) __builtin_amdgcn_exp2f(x)
#else
#define EXP2F(x) __expf((x) * 0.69314718056f)
#endif

// async global->LDS, 16B per lane; LDS dest = wave-uniform base + lane*16
__device__ __forceinline__ void gload_lds16(const u16* g, u16* l) {
    __builtin_amdgcn_global_load_lds(
        (__attribute__((address_space(1))) void*)(g),
        (__attribute__((address_space(3))) void*)(l), 16, 0, 0);
}

// --------------------------------------- fp32 -> bf16 cast, all 3 inputs fused
__global__ __launch_bounds__(256) void cast_all_k(const float* __restrict__ x,
                                                  const float* __restrict__ wq,
                                                  const float* __restrict__ wp,
                                                  u16* __restrict__ xo,
                                                  u16* __restrict__ wqo,
                                                  u16* __restrict__ wpo) {
    int i = blockIdx.x * 256 + threadIdx.x;      // 0..3145727 (x4 elems)
    const float* src; u16* dst; int off;
    if (i < 2097152)      { src = x;  dst = xo;  off = i; }
    else if (i < 2883584) { src = wq; dst = wqo; off = i - 2097152; }
    else                  { src = wp; dst = wpo; off = i - 2883584; }
    float4 v = *(const float4*)&src[(size_t)off * 4];
    u16 tmp[4] = {f2bf(v.x), f2bf(v.y), f2bf(v.z), f2bf(v.w)};
    *(ushort4*)&dst[(size_t)off * 4] = *(ushort4*)tmp;
}

// ---------------------------------------------------------------- rope table
__global__ __launch_bounds__(256) void rope_table_k(float* __restrict__ cosT,
                                                    float* __restrict__ sinT) {
    int idx = blockIdx.x * 256 + threadIdx.x;    // L*32 = 65536
    int l = idx >> 5, i = idx & 31;
    float invf = exp2f(-(float)i * 0.41524101186092029f);  // log2(10000)/32
    float ang = (float)l * invf;
    cosT[idx] = cosf(ang);
    sinT[idx] = sinf(ang);
}

// ---------------------------------------------------- NT GEMM: C = A * B^T
// A [M][K] bf16, B [N][K] bf16, C [M][N] (bf16 or fp32). M%128, N%128, K%64 == 0.
// Staging via global_load_lds(16B); unpadded LDS with XOR chunk swizzle.
template <typename OutT>
__global__ __launch_bounds__(256) void gemm_bt(const u16* __restrict__ A,
                                               const u16* __restrict__ Bm,
                                               OutT* __restrict__ C,
                                               int M, int N, int K) {
    __shared__ u16 As[128][64];
    __shared__ u16 Bs[128][64];
    const int t = threadIdx.x;
    const int lane = t & 63, wave = t >> 6;
    const int quad = lane >> 4, lrow = lane & 15;
    const int wr = wave >> 1, wc = wave & 1;
    const size_t m0 = (size_t)blockIdx.y * 128, n0 = (size_t)blockIdx.x * 128;

    const int srow = wave * 32 + (lane >> 3);       // +j*8 covers 32 rows/wave
    const int scg  = (lane & 7) ^ (lane >> 3);      // swizzled global chunk

    f32x4 acc[4][4];
#pragma unroll
    for (int i = 0; i < 4; ++i)
#pragma unroll
        for (int j = 0; j < 4; ++j) acc[i][j] = (f32x4)0.0f;

    for (int k0 = 0; k0 < K; k0 += 64) {
#pragma unroll
        for (int j = 0; j < 4; ++j) {
            gload_lds16(&A[(m0 + srow + j * 8) * K + k0 + scg * 8],
                        &As[wave * 32 + j * 8][0]);
            gload_lds16(&Bm[(n0 + srow + j * 8) * K + k0 + scg * 8],
                        &Bs[wave * 32 + j * 8][0]);
        }
        __syncthreads();
#pragma unroll
        for (int ks = 0; ks < 2; ++ks) {
            bf16x8 av[4], bv[4];
#pragma unroll
            for (int i = 0; i < 4; ++i)
                av[i] = *(const bf16x8*)
                    &As[wr * 64 + i * 16 + lrow][(((ks << 2) | quad) ^ (lrow & 7)) << 3];
#pragma unroll
            for (int j = 0; j < 4; ++j)
                bv[j] = *(const bf16x8*)
                    &Bs[wc * 64 + j * 16 + lrow][(((ks << 2) | quad) ^ (lrow & 7)) << 3];
#pragma unroll
            for (int i = 0; i < 4; ++i)
#pragma unroll
                for (int j = 0; j < 4; ++j)
                    acc[i][j] = __builtin_amdgcn_mfma_f32_16x16x32_bf16(
                        av[i], bv[j], acc[i][j], 0, 0, 0);
        }
        __syncthreads();
    }
    // C/D layout: col = lane&15, row = quad*4 + r
#pragma unroll
    for (int i = 0; i < 4; ++i)
#pragma unroll
        for (int r = 0; r < 4; ++r) {
            size_t row = m0 + wr * 64 + i * 16 + quad * 4 + r;
#pragma unroll
            for (int j = 0; j < 4; ++j) {
                size_t col = n0 + wc * 64 + j * 16 + lrow;
                if constexpr (sizeof(OutT) == 4)
                    C[row * N + col] = acc[i][j][r];
                else
                    C[row * N + col] = f2bf(acc[i][j][r]);
            }
        }
}

// --------------- fused RoPE(q,k) + V-transpose: one pass over the qkv buffer
// grid (32 l-tiles, 64 bh), 256 thr. Q,K -> [BH][L][64] rope'd; V -> VT [BH*64][L].
__global__ __launch_bounds__(256) void rope_vt_k(const u16* __restrict__ qkv,
                                                 const float* __restrict__ cosT,
                                                 const float* __restrict__ sinT,
                                                 u16* __restrict__ Q,
                                                 u16* __restrict__ Ko,
                                                 u16* __restrict__ VT) {
    __shared__ u16 vtile[64][72];
    const int lt = blockIdx.x, bh = blockIdx.y;
    const int b = bh >> 4, h = bh & 15;
    const int l0 = lt * 64;
    const int t = threadIdx.x;
    const float SC = 0.180336879f;       // 1/8 * log2(e): exp2-ready logits
#pragma unroll
    for (int c = 0; c < 2; ++c) {
        int flat8 = c * 256 + t;         // 0..511
        int li = flat8 >> 3, dg = flat8 & 7;
        const u16* rowp = qkv + (size_t)(b * NL + l0 + li) * 3072 + h * 64 + dg * 8;
        uint4 qv = *(const uint4*)rowp;
        uint4 kv = *(const uint4*)(rowp + 1024);
        uint4 vv = *(const uint4*)(rowp + 2048);
        *(uint4*)&vtile[li][dg * 8] = vv;
        float4 cs = *(const float4*)&cosT[(l0 + li) * 32 + dg * 4];
        float4 sn = *(const float4*)&sinT[(l0 + li) * 32 + dg * 4];
        union { float f; u32 u; } w;
        float e0, o0, e1, o1, e2, o2, e3, o3;
        w.u = qv.x << 16; e0 = w.f; w.u = qv.x & 0xffff0000u; o0 = w.f;
        w.u = qv.y << 16; e1 = w.f; w.u = qv.y & 0xffff0000u; o1 = w.f;
        w.u = qv.z << 16; e2 = w.f; w.u = qv.z & 0xffff0000u; o2 = w.f;
        w.u = qv.w << 16; e3 = w.f; w.u = qv.w & 0xffff0000u; o3 = w.f;
        float c0 = cs.x * SC, c1 = cs.y * SC, c2 = cs.z * SC, c3 = cs.w * SC;
        float s0 = sn.x * SC, s1 = sn.y * SC, s2 = sn.z * SC, s3 = sn.w * SC;
        size_t ob = ((size_t)(b * NH + h) * NL + l0 + li) * 64;
        *(uint2*)&Q[ob + dg * 4] =
            make_uint2(pk2(e0 * c0 - o0 * s0, e1 * c1 - o1 * s1),
                       pk2(e2 * c2 - o2 * s2, e3 * c3 - o3 * s3));
        *(uint2*)&Q[ob + 32 + dg * 4] =
            make_uint2(pk2(e0 * s0 + o0 * c0, e1 * s1 + o1 * c1),
                       pk2(e2 * s2 + o2 * c2, e3 * s3 + o3 * c3));
        float f0, g0, f1, g1, f2, g2, f3, g3;
        w.u = kv.x << 16; f0 = w.f; w.u = kv.x & 0xffff0000u; g0 = w.f;
        w.u = kv.y << 16; f1 = w.f; w.u = kv.y & 0xffff0000u; g1 = w.f;
        w.u = kv.z << 16; f2 = w.f; w.u = kv.z & 0xffff0000u; g2 = w.f;
        w.u = kv.w << 16; f3 = w.f; w.u = kv.w & 0xffff0000u; g3 = w.f;
        *(uint2*)&Ko[ob + dg * 4] =
            make_uint2(pk2(f0 * cs.x - g0 * sn.x, f1 * cs.y - g1 * sn.y),
                       pk2(f2 * cs.z - g2 * sn.z, f3 * cs.w - g3 * sn.w));
        *(uint2*)&Ko[ob + 32 + dg * 4] =
            make_uint2(pk2(f0 * sn.x + g0 * cs.x, f1 * sn.y + g1 * cs.y),
                       pk2(f2 * sn.z + g2 * cs.z, f3 * sn.w + g3 * cs.w));
    }
    __syncthreads();
#pragma unroll
    for (int c = 0; c < 2; ++c) {
        int flat8 = c * 256 + t;
        int d = flat8 >> 3, lg = flat8 & 7;
        u16 tmp[8];
#pragma unroll
        for (int e = 0; e < 8; ++e) tmp[e] = vtile[lg * 8 + e][d];
        *(uint4*)&VT[((size_t)(bh * 64 + d)) * NL + l0 + lg * 8] = *(uint4*)tmp;
    }
}

// --------------------------------------------- flash attention (MFMA)
// 4 waves x 64 q (4 halves of 16 sharing every K/V read). S^T = K.Q^T puts
// P in C/D layout (row=key=quad*4+r, col=q) == A-operand layout of the K=16
// MFMA 16x16x16bf16 -> O = P.V with P DIRECTLY FROM REGISTERS (no LDS
// round-trip, no epilogue transpose: O rows=q, cols=d). L via B=ones MFMA
// (same row=q layout). Single barrier/chunk + K/V double-buffer prefetch.
// XCD swizzle: all 8 q-tiles of a bh land on one XCD -> K/V L2-resident.
__global__ __launch_bounds__(256, 2) void attn_k(const u16* __restrict__ Q,
                                                 const u16* __restrict__ Kg,
                                                 const u16* __restrict__ VT,
                                                 u16* __restrict__ Og) {
    __shared__ __align__(16) char smem[65536];
    u16 (*KsB)[64][64] = (u16(*)[64][64])(smem);           // 2 bufs @0, 8192
    u16 (*VsB)[64][64] = (u16(*)[64][64])(smem + 16384);   // 2 bufs @16384, 24576
    u16 (*Qtmp)[64]    = (u16(*)[64])(smem + 32768);       // 256 q x 64 d (wave-private 8KB each)
    const int t = threadIdx.x;
    const int lane = t & 63, wave = t >> 6;                // wave 0..3
    const int quad = lane >> 4, lq = lane & 15;

    const int flat = blockIdx.x;                           // 0..511
    const int bh = (flat & 7) | ((flat >> 6) << 3);        // same-bh blocks: same XCD (mod 8)
    const int qt = (flat >> 3) & 7;
    const int q0 = qt * 256;
    const size_t qkbase = (size_t)bh * NL * 64;

    const int rsub = lane >> 3;                            // 0..7
    const int scg  = (lane & 7) ^ rsub;                    // swizzled global chunk

    // preloop: stage this wave's 64 Q rows (own Qtmp region) + prefetch chunk 0
#pragma unroll
    for (int j = 0; j < 8; ++j)
        gload_lds16(&Q[qkbase + (size_t)(q0 + wave * 64 + j * 8 + rsub) * 64 + scg * 8],
                    &Qtmp[wave * 64 + j * 8][0]);
    const u16* kptr = Kg + qkbase + (size_t)(wave * 16 + rsub) * 64 + scg * 8;
    const u16* vptr = VT + qkbase + (size_t)(wave * 16 + rsub) * NL + scg * 8;
#pragma unroll
    for (int j = 0; j < 2; ++j) {
        gload_lds16(kptr + (size_t)j * 8 * 64, &KsB[0][wave * 16 + j * 8][0]);
        gload_lds16(vptr + (size_t)j * 8 * NL, &VsB[0][wave * 16 + j * 8][0]);
    }
    kptr += 64 * 64;
    vptr += 64;
    __syncthreads();                      // Q + chunk0 resident
    bf16x8 bq[4][2];                      // Q frags: invariant across chunks
#pragma unroll
    for (int qh = 0; qh < 4; ++qh)
#pragma unroll
        for (int ks = 0; ks < 2; ++ks)
            bq[qh][ks] = *(const bf16x8*)
                &Qtmp[wave * 64 + qh * 16 + lq][(((ks << 2) | quad) ^ (lq & 7)) << 3];

    const bf16x4 ones4 = (bf16x4)(short)16256;             // bf16 1.0 splat
    f32x4 ot[4][4];                       // O[q=quad*4+r][d=dt*16+lq] per qh
#pragma unroll
    for (int qh = 0; qh < 4; ++qh)
#pragma unroll
        for (int dt = 0; dt < 4; ++dt) ot[qh][dt] = (f32x4)0.0f;
    f32x4 lacc[4] = {(f32x4)0.0f, (f32x4)0.0f, (f32x4)0.0f, (f32x4)0.0f};

    const int lq7 = lq & 7, qh1 = quad >> 1, ql = (quad & 1) * 4;

    for (int kc = 0; kc < NL / 64; ++kc) {
        __syncthreads();                  // prev chunk consumed; prefetch landed
        if (kc < NL / 64 - 1) {
#pragma unroll
            for (int j = 0; j < 2; ++j) {
                gload_lds16(kptr + (size_t)j * 8 * 64, &KsB[(kc + 1) & 1][wave * 16 + j * 8][0]);
                gload_lds16(vptr + (size_t)j * 8 * NL, &VsB[(kc + 1) & 1][wave * 16 + j * 8][0]);
            }
            kptr += 64 * 64;
            vptr += 64;
        }
        const int cur = kc & 1;

        // S^T = K_chunk (64k x 64d) . Q^T (64d x 64q); K frag shared by 4 halves
        f32x4 st[4][4];
#pragma unroll
        for (int qh = 0; qh < 4; ++qh)
#pragma unroll
            for (int mt = 0; mt < 4; ++mt) st[qh][mt] = (f32x4)0.0f;
#pragma unroll
        for (int ks = 0; ks < 2; ++ks)
#pragma unroll
            for (int mt = 0; mt < 4; ++mt) {
                bf16x8 ak = *(const bf16x8*)
                    &KsB[cur][mt * 16 + lq][(((ks << 2) | quad) ^ lq7) << 3];
#pragma unroll
                for (int qh = 0; qh < 4; ++qh)
                    st[qh][mt] = __builtin_amdgcn_mfma_f32_16x16x32_bf16(
                        ak, bq[qh][ks], st[qh][mt], 0, 0, 0);
            }

        // p = exp2(s), trunc-pack into A-operand frags (k = quad*4 + j): in-register!
        bf16x4 pa[4][4];
#pragma unroll
        for (int qh = 0; qh < 4; ++qh)
#pragma unroll
            for (int mt = 0; mt < 4; ++mt) {
                union { uint2 u; bf16x4 v; } c;
                c.u = make_uint2(pkt(EXP2F(st[qh][mt][0]), EXP2F(st[qh][mt][1])),
                                 pkt(EXP2F(st[qh][mt][2]), EXP2F(st[qh][mt][3])));
                pa[qh][mt] = c.v;
            }

        // O += P.V (K=16 MFMA, A=P from regs, B=V b64 from LDS); L += P.ones
#pragma unroll
        for (int mt = 0; mt < 4; ++mt) {
#pragma unroll
            for (int qh = 0; qh < 4; ++qh)
                lacc[qh] = __builtin_amdgcn_mfma_f32_16x16x16bf16_1k(
                    pa[qh][mt], ones4, lacc[qh], 0, 0, 0);
            const int voff = ((mt * 2 + qh1) ^ lq7) * 8 + ql;
#pragma unroll
            for (int dt = 0; dt < 4; ++dt) {
                bf16x4 bv = *(const bf16x4*)&VsB[cur][dt * 16 + lq][voff];
#pragma unroll
                for (int qh = 0; qh < 4; ++qh)
                    ot[qh][dt] = __builtin_amdgcn_mfma_f32_16x16x16bf16_1k(
                        pa[qh][mt], bv, ot[qh][dt], 0, 0, 0);
            }
        }
    }

    // epilogue: O rows=q (quad*4+r), cols=d (dt*16+lq) -- direct stores, no LDS
    const int b = bh >> 4, h = bh & 15;
#pragma unroll
    for (int qh = 0; qh < 4; ++qh)
#pragma unroll
        for (int r = 0; r < 4; ++r) {
            float rls = 1.0f / lacc[qh][r];
            size_t row = (size_t)b * NL + q0 + wave * 64 + qh * 16 + quad * 4 + r;
            size_t obase = row * 1024 + h * 64 + lq;
#pragma unroll
            for (int dt = 0; dt < 4; ++dt)
                Og[obase + dt * 16] = f2bf(ot[qh][dt][r] * rls);
        }
}

// ----------------------------------------------------------------- launch
extern "C" void kernel_launch(void* const* d_in, const int* in_sizes, int n_in,
                              void* d_out, int out_size, void* d_ws, size_t ws_size,
                              hipStream_t stream) {
    const float* x     = (const float*)d_in[0];   // [8192][1024] fp32
    const float* Wqkv  = (const float*)d_in[1];   // [3072][1024] fp32
    const float* Wproj = (const float*)d_in[2];   // [1024][1024] fp32
    float* out = (float*)d_out;                   // [8192][1024] fp32

    char* ws = (char*)d_ws;
    u16* qkv     = (u16*)ws;                      // 50,331,648 B
    u16* attnout = (u16*)ws;                      // reuses qkv region (dead by then)
    u16* Qw      = (u16*)(ws + 50331648);         // 16,777,216 B
    u16* Kw      = (u16*)(ws + 67108864);         // 16,777,216 B
    u16* VTw     = (u16*)(ws + 83886080);         // 16,777,216 B
    float* cosT  = (float*)(ws + 100663296);      //    262,144 B
    float* sinT  = (float*)(ws + 100925440);      //    262,144 B
    u16* x_bf    = (u16*)(ws + 101187584);        // 16,777,216 B
    u16* Wqkv_bf = (u16*)(ws + 117964800);        //  6,291,456 B
    u16* Wproj_bf= (u16*)(ws + 124256256);        //  2,097,152 B  (total ~126.4 MB)

    rope_table_k<<<256, 256, 0, stream>>>(cosT, sinT);
    cast_all_k<<<12288, 256, 0, stream>>>(x, Wqkv, Wproj, x_bf, Wqkv_bf, Wproj_bf);
    gemm_bt<u16><<<dim3(24, 64), 256, 0, stream>>>(x_bf, Wqkv_bf, qkv, 8192, 3072, 1024);
    rope_vt_k<<<dim3(32, 64), 256, 0, stream>>>(qkv, cosT, sinT, Qw, Kw, VTw);
    attn_k<<<dim3(512), 256, 0, stream>>>(Qw, Kw, VTw, attnout);
    gemm_bt<float><<<dim3(8, 64), 256, 0, stream>>>(attnout, Wproj_bf, out, 8192, 1024, 1024);
}